// Round 11
// baseline (127.031 us; speedup 1.0000x reference)
//
#include <hip/hip_runtime.h>

// Density-Aware Chamfer Loss, B=8, N=M=4096, fp32.
// Round 11: MFMA-hybrid. Pairwise dot products (the dominant VALU cost) move
// to the matrix cores via bf16 h+m+l split (18-slot K-packing, exact to ~1e-5).
// Epilogue on VALU: cross 2add+2min/pair (dual mins), dens 2add+exp2+2acc.
// Zero atomics; exclusive partial arrays (round-8 discipline).

#define NB 8
#define NPTS 4096
#define PTSTOT 32768
#define BIGF 3.4e38f
#define OFFD_BLKS 2176      // 16 (cl,b) * 136 chunks
#define CROSS_BLKS 1024     // b(8) * strip I(32) * phase(4)
#define DIAG_BLKS 512       // cl(2) * b(8) * strip(32)
#define TRISLOT 3968        // packed (J-group, strip) col-partial slots

typedef __attribute__((ext_vector_type(8))) short bf16x8;
typedef __attribute__((ext_vector_type(4))) float f32x4;

__device__ __forceinline__ unsigned bf16rne(float x){
    unsigned u = __float_as_uint(x);
    return (u + 0x7FFFu + ((u>>16)&1u)) >> 16;
}
__device__ __forceinline__ void split1(float x, unsigned& h, unsigned& m, unsigned& l){
    h = bf16rne(x);
    float r1 = x - __uint_as_float(h<<16);
    m = bf16rne(r1);
    l = bf16rne(r1 - __uint_as_float(m<<16));
}
// A-layout: per dim slots [h,h,m,m,h,l]; k = x:0-5, y:6-11, z:12-17; q=(lane>>4) covers k=8q..8q+7
__device__ __forceinline__ void packA(uint4* a, int base,
    unsigned hx,unsigned mx,unsigned lx, unsigned hy,unsigned my,unsigned ly,
    unsigned hz,unsigned mz,unsigned lz)
{
    a[base]    = make_uint4(hx|(hx<<16), mx|(mx<<16), hx|(lx<<16), hy|(hy<<16));
    a[base+16] = make_uint4(my|(my<<16), hy|(ly<<16), hz|(hz<<16), mz|(mz<<16));
    a[base+32] = make_uint4(hz|(lz<<16), 0u, 0u, 0u);
    a[base+48] = make_uint4(0u,0u,0u,0u);
}
// B-layout: per dim slots [h,m,h,m,l,h]
__device__ __forceinline__ void packB(uint4* a, int base,
    unsigned hx,unsigned mx,unsigned lx, unsigned hy,unsigned my,unsigned ly,
    unsigned hz,unsigned mz,unsigned lz)
{
    a[base]    = make_uint4(hx|(mx<<16), hx|(mx<<16), lx|(hx<<16), hy|(my<<16));
    a[base+16] = make_uint4(hy|(my<<16), ly|(hy<<16), hz|(mz<<16), hz|(mz<<16));
    a[base+32] = make_uint4(lz|(hz<<16), 0u, 0u, 0u);
    a[base+48] = make_uint4(0u,0u,0u,0u);
}

__global__ __launch_bounds__(256) void dacl_prep(
    const float* __restrict__ pred, const float* __restrict__ gt,
    const float* __restrict__ bwp,  const float* __restrict__ bwg,
    uint4* __restrict__ Ac, uint4* __restrict__ Bc,
    uint4* __restrict__ Ap, uint4* __restrict__ Bp,
    uint4* __restrict__ Ag, uint4* __restrict__ Bg,
    float* __restrict__ rrP, float* __restrict__ ccG,
    float* __restrict__ ndP, float* __restrict__ ndG)
{
    const int gid  = blockIdx.x*256 + threadIdx.x;   // [0, 65536)
    const int cl   = gid >> 15;
    const int pidx = gid & 32767;
    const int base = ((pidx>>4)<<6) + (pidx & 15);   // group*64 + row
    const float* s = (cl ? gt : pred) + (size_t)pidx*3;
    const float x = s[0], y = s[1], z = s[2];
    const float n2 = x*x + y*y + z*z;
    const float bw = cl ? bwg[0] : bwp[0];
    const float s2 = 0.5f / (bw*bw*0.6931471805599453f);
    const float q  = sqrtf(2.0f*s2);

    unsigned hx,mx,lx,hy,my,ly,hz,mz,lz;
    if (cl == 0) {
        split1(-2.f*x,hx,mx,lx); split1(-2.f*y,hy,my,ly); split1(-2.f*z,hz,mz,lz);
        packA(Ac, base, hx,mx,lx,hy,my,ly,hz,mz,lz);
        split1(q*x,hx,mx,lx); split1(q*y,hy,my,ly); split1(q*z,hz,mz,lz);
        packA(Ap, base, hx,mx,lx,hy,my,ly,hz,mz,lz);
        packB(Bp, base, hx,mx,lx,hy,my,ly,hz,mz,lz);
        rrP[pidx] = n2; ndP[pidx] = -s2*n2;
    } else {
        split1(x,hx,mx,lx); split1(y,hy,my,ly); split1(z,hz,mz,lz);
        packB(Bc, base, hx,mx,lx,hy,my,ly,hz,mz,lz);
        split1(q*x,hx,mx,lx); split1(q*y,hy,my,ly); split1(q*z,hz,mz,lz);
        packA(Ag, base, hx,mx,lx,hy,my,ly,hz,mz,lz);
        packB(Bg, base, hx,mx,lx,hy,my,ly,hz,mz,lz);
        ccG[pidx] = n2; ndG[pidx] = -s2*n2;
    }
}

__global__ __launch_bounds__(256) void dacl_pairs(
    const uint4* __restrict__ Ac, const uint4* __restrict__ Bc,
    const uint4* __restrict__ Ap, const uint4* __restrict__ Bp,
    const uint4* __restrict__ Ag, const uint4* __restrict__ Bg,
    const float* __restrict__ rrP, const float* __restrict__ ccG,
    const float* __restrict__ ndP, const float* __restrict__ ndG,
    float* __restrict__ minP2Gp,   // [4 ph][PTSTOT]
    float* __restrict__ minG2Pp,   // [32 I][PTSTOT]
    float* __restrict__ densRowP,  // [9 slot][2 cl][PTSTOT]
    float* __restrict__ densCol)   // [16 clb][TRISLOT][16]
{
    __shared__ float sRed[4][128];
    const int tid  = threadIdx.x;
    const int lane = tid & 63;
    const int w    = tid >> 6;
    const int lq   = lane >> 4;
    const int lr   = lane & 15;
    const int bid  = blockIdx.x;
    const f32x4 z4 = {0.f,0.f,0.f,0.f};

    if (bid < OFFD_BLKS) {
        // ====== density off-diagonal: (cl,b,strip u, chunk cj of 32 J-groups)
        const int clb = bid / 136;
        int rem = bid - clb*136;
        const int b = clb & 7, cl = clb >> 3;
        int u = 0;
        for (; u < 31; ++u) { int nch = (279 - 8*u) >> 5; if (rem < nch) break; rem -= nch; }
        const int cj = rem;
        const int J0 = 8*u + 8 + 32*cj;

        const uint4* Aarr = cl ? Ag : Ap;
        const uint4* Barr = cl ? Bg : Bp;
        const float* nd   = cl ? ndG : ndP;
        float* dCol = densCol + (size_t)clb * (TRISLOT*16);

        bf16x8 af[8]; f32x4 ndr[8]; float racc[8][4];
        #pragma unroll
        for (int g = 0; g < 8; ++g) {
            af[g]  = *((const bf16x8*)(Aarr + (size_t)((b*256 + u*8 + g)*64 + lane)));
            ndr[g] = *((const f32x4*)(nd + b*4096 + u*128 + g*16 + lq*4));
            #pragma unroll
            for (int r = 0; r < 4; ++r) racc[g][r] = 0.f;
        }

        for (int t = 0; t < 8; ++t) {
            const int J = J0 + w*8 + t;
            if (J < 256) {
                bf16x8 bfv = *((const bf16x8*)(Barr + (size_t)((b*256 + J)*64 + lane)));
                const float ndcv = nd[b*4096 + J*16 + lr];
                float ca = 0.f;
                #pragma unroll
                for (int g = 0; g < 8; ++g) {
                    f32x4 acc = __builtin_amdgcn_mfma_f32_16x16x32_bf16(af[g], bfv, z4, 0,0,0);
                    #pragma unroll
                    for (int r = 0; r < 4; ++r) {
                        float e = (acc[r] + ndr[g][r]) + ndcv;   // = -(s*d)^2
                        float k = __builtin_amdgcn_exp2f(e);
                        racc[g][r] += k;
                        ca += k;
                    }
                }
                ca += __shfl_xor(ca, 16, 64);
                ca += __shfl_xor(ca, 32, 64);
                const int q8 = J >> 3, r8 = J & 7;
                const int baseJ = 4*q8*(q8-1) + r8*q8;
                if (lane < 16) dCol[(baseJ + u)*16 + lane] = ca;
            }
        }
        // row flush: sum across waves (different J sets)
        #pragma unroll
        for (int g = 0; g < 8; ++g)
            #pragma unroll
            for (int r = 0; r < 4; ++r) {
                float v = racc[g][r];
                v += __shfl_xor(v, 1, 64);
                v += __shfl_xor(v, 2, 64);
                v += __shfl_xor(v, 4, 64);
                v += __shfl_xor(v, 8, 64);
                if (lr == 0) sRed[w][g*16 + lq*4 + r] = v;
            }
        __syncthreads();
        if (tid < 128) {
            float v = (sRed[0][tid] + sRed[1][tid]) + (sRed[2][tid] + sRed[3][tid]);
            densRowP[(size_t)((cj+1)*2 + cl)*PTSTOT + b*4096 + u*128 + tid] = v;
        }
    } else if (bid < OFFD_BLKS + CROSS_BLKS) {
        // ====== cross: (b, pred strip I, J-quarter ph), dual mins ======
        const int cb = bid - OFFD_BLKS;
        const int b = cb >> 7, I = (cb >> 2) & 31, ph = cb & 3;

        bf16x8 af[8]; f32x4 rr[8]; float rmin[8][4];
        #pragma unroll
        for (int g = 0; g < 8; ++g) {
            af[g] = *((const bf16x8*)(Ac + (size_t)((b*256 + I*8 + g)*64 + lane)));
            rr[g] = *((const f32x4*)(rrP + b*4096 + I*128 + g*16 + lq*4));
            #pragma unroll
            for (int r = 0; r < 4; ++r) rmin[g][r] = BIGF;
        }

        for (int t = 0; t < 16; ++t) {
            const int J = ph*64 + w*16 + t;
            bf16x8 bfv = *((const bf16x8*)(Bc + (size_t)((b*256 + J)*64 + lane)));
            const float ccv = ccG[b*4096 + J*16 + lr];
            float cm = BIGF;
            #pragma unroll
            for (int g = 0; g < 8; ++g) {
                f32x4 acc = __builtin_amdgcn_mfma_f32_16x16x32_bf16(af[g], bfv, z4, 0,0,0);
                #pragma unroll
                for (int r = 0; r < 4; ++r) {
                    rmin[g][r] = fminf(rmin[g][r], acc[r] + ccv);  // +rr at flush
                    cm         = fminf(cm,         acc[r] + rr[g][r]);
                }
            }
            cm = fminf(cm, __shfl_xor(cm, 16, 64));
            cm = fminf(cm, __shfl_xor(cm, 32, 64));
            if (lane < 16)
                minG2Pp[(size_t)I*PTSTOT + b*4096 + J*16 + lane] = cm + ccv;
        }
        // row flush: min across waves
        #pragma unroll
        for (int g = 0; g < 8; ++g)
            #pragma unroll
            for (int r = 0; r < 4; ++r) {
                float v = rmin[g][r] + rr[g][r];
                v = fminf(v, __shfl_xor(v, 1, 64));
                v = fminf(v, __shfl_xor(v, 2, 64));
                v = fminf(v, __shfl_xor(v, 4, 64));
                v = fminf(v, __shfl_xor(v, 8, 64));
                if (lr == 0) sRed[w][g*16 + lq*4 + r] = v;
            }
        __syncthreads();
        if (tid < 128) {
            float v = fminf(fminf(sRed[0][tid], sRed[1][tid]),
                            fminf(sRed[2][tid], sRed[3][tid]));
            minP2Gp[(size_t)ph*PTSTOT + b*4096 + I*128 + tid] = v;
        }
    } else {
        // ====== density diagonal strip blocks: full 8x8 groups, rows-only ====
        const int db = bid - (OFFD_BLKS + CROSS_BLKS);
        const int b = db & 7, u = (db >> 3) & 31, cl = db >> 8;
        const uint4* Aarr = cl ? Ag : Ap;
        const uint4* Barr = cl ? Bg : Bp;
        const float* nd   = cl ? ndG : ndP;

        const int gA0 = w*2;
        bf16x8 af[2]; f32x4 ndr[2]; float racc[2][4];
        #pragma unroll
        for (int i = 0; i < 2; ++i) {
            const int g = gA0 + i;
            af[i]  = *((const bf16x8*)(Aarr + (size_t)((b*256 + u*8 + g)*64 + lane)));
            ndr[i] = *((const f32x4*)(nd + b*4096 + u*128 + g*16 + lq*4));
            #pragma unroll
            for (int r = 0; r < 4; ++r) racc[i][r] = 0.f;
        }
        for (int gB = 0; gB < 8; ++gB) {
            bf16x8 bfv = *((const bf16x8*)(Barr + (size_t)((b*256 + u*8 + gB)*64 + lane)));
            const float ndcv = nd[b*4096 + u*128 + gB*16 + lr];
            #pragma unroll
            for (int i = 0; i < 2; ++i) {
                f32x4 acc = __builtin_amdgcn_mfma_f32_16x16x32_bf16(af[i], bfv, z4, 0,0,0);
                #pragma unroll
                for (int r = 0; r < 4; ++r) {
                    float e = (acc[r] + ndr[i][r]) + ndcv;
                    racc[i][r] += __builtin_amdgcn_exp2f(e);
                }
            }
        }
        // rows exclusive per wave -> direct store to diag slot 0
        #pragma unroll
        for (int i = 0; i < 2; ++i)
            #pragma unroll
            for (int r = 0; r < 4; ++r) {
                float v = racc[i][r];
                v += __shfl_xor(v, 1, 64);
                v += __shfl_xor(v, 2, 64);
                v += __shfl_xor(v, 4, 64);
                v += __shfl_xor(v, 8, 64);
                if (lr == 0)
                    densRowP[(size_t)cl*PTSTOT + b*4096 + u*128 + (gA0+i)*16 + lq*4 + r] = v;
            }
    }
}

__global__ __launch_bounds__(256) void dacl_combine(
    const float* __restrict__ minP2Gp, const float* __restrict__ minG2Pp,
    const float* __restrict__ densRowP, const float* __restrict__ densCol,
    float* __restrict__ bsum)
{
    const int g   = blockIdx.x*256 + threadIdx.x;   // [0, 65536)
    const int dir = g >> 15;
    const int idx = g & 32767;
    const int b   = idx >> 12;
    const int pt  = idx & 4095;
    const int cl  = dir;

    float m = BIGF;
    if (dir == 0) {
        #pragma unroll
        for (int s = 0; s < 4; ++s) m = fminf(m, minP2Gp[(size_t)s*PTSTOT + idx]);
    } else {
        #pragma unroll
        for (int s = 0; s < 32; ++s) m = fminf(m, minG2Pp[(size_t)s*PTSTOT + idx]);
    }
    m = fmaxf(m, 0.0f);

    float dn = densRowP[(size_t)cl*PTSTOT + idx];   // diag slot
    const int u = pt >> 7;
    const int nch = (279 - 8*u) >> 5;
    #pragma unroll
    for (int k = 1; k <= 8; ++k)
        if (k <= nch) dn += densRowP[(size_t)(k*2 + cl)*PTSTOT + idx];
    const int T = pt >> 4;
    const int q8 = T >> 3;
    const int baseT = 4*q8*(q8-1) + (T&7)*q8;
    const float* dC = densCol + (size_t)(cl*8 + b)*(TRISLOT*16) + (pt & 15);
    for (int up = 0; up < q8; ++up) dn += dC[(baseT + up)*16];

    float val = m / (dn * (1.0f/4095.0f) + 1e-6f) * (1.0f/32768.0f);

    #pragma unroll
    for (int off = 32; off; off >>= 1) val += __shfl_down(val, off);
    __shared__ float sm[4];
    const int lane = threadIdx.x & 63, wid = threadIdx.x >> 6;
    if (lane == 0) sm[wid] = val;
    __syncthreads();
    if (threadIdx.x == 0) bsum[blockIdx.x] = (sm[0] + sm[1]) + (sm[2] + sm[3]);
}

__global__ __launch_bounds__(256) void dacl_final(
    const float* __restrict__ bsum, float* __restrict__ out)
{
    float v = bsum[threadIdx.x];
    #pragma unroll
    for (int off = 32; off; off >>= 1) v += __shfl_down(v, off);
    __shared__ float sm[4];
    const int lane = threadIdx.x & 63, wid = threadIdx.x >> 6;
    if (lane == 0) sm[wid] = v;
    __syncthreads();
    if (threadIdx.x == 0) out[0] = (sm[0] + sm[1]) + (sm[2] + sm[3]);
}

extern "C" void kernel_launch(void* const* d_in, const int* in_sizes, int n_in,
                              void* d_out, int out_size, void* d_ws, size_t ws_size,
                              hipStream_t stream)
{
    const float* pred = (const float*)d_in[0];
    const float* gt   = (const float*)d_in[1];
    const float* bwp  = (const float*)d_in[2];
    const float* bwg  = (const float*)d_in[3];

    uint4* Ac = (uint4*)d_ws;            // 6 pack arrays x 131072 uint4 (2 MB each)
    uint4* Bc = Ac + 131072;
    uint4* Ap = Bc + 131072;
    uint4* Bp = Ap + 131072;
    uint4* Ag = Bp + 131072;
    uint4* Bg = Ag + 131072;
    float* rrP = (float*)(Bg + 131072);          // [32768]
    float* ccG = rrP + PTSTOT;
    float* ndP = ccG + PTSTOT;
    float* ndG = ndP + PTSTOT;
    float* minP2Gp  = ndG + PTSTOT;              // [4][32768]
    float* minG2Pp  = minP2Gp + 4*(size_t)PTSTOT;   // [32][32768]
    float* densRowP = minG2Pp + 32*(size_t)PTSTOT;  // [18][32768]
    float* densCol  = densRowP + 18*(size_t)PTSTOT; // [16][3968][16]
    float* bsum     = densCol + (size_t)16*TRISLOT*16;

    dacl_prep<<<256, 256, 0, stream>>>(pred, gt, bwp, bwg,
                                       Ac, Bc, Ap, Bp, Ag, Bg,
                                       rrP, ccG, ndP, ndG);
    dacl_pairs<<<OFFD_BLKS + CROSS_BLKS + DIAG_BLKS, 256, 0, stream>>>(
        Ac, Bc, Ap, Bp, Ag, Bg, rrP, ccG, ndP, ndG,
        minP2Gp, minG2Pp, densRowP, densCol);
    dacl_combine<<<256, 256, 0, stream>>>(minP2Gp, minG2Pp, densRowP, densCol, bsum);
    dacl_final<<<1, 256, 0, stream>>>(bsum, (float*)d_out);
}

// Round 12
// 116.323 us; speedup vs baseline: 1.0921x; 1.0921x over previous
//
#include <hip/hip_runtime.h>

// Density-Aware Chamfer Loss, B=8, N=M=4096, fp32.
// Round 12: Morton-sort + tile-level AABB skip on top of the round-10
// structure (zero atomics, exclusive partials). kde=exp2(-72 d^2) -> pairs
// with d^2>0.42 contribute <2^-30; NN dists ~0.1 -> most of the 270M pair
// evals are dead work. Sorted 128-pt tiles are compact -> skip whole tiles.

#define NPTS 4096
#define NB   8
#define TS   128
#define TPB  256
#define BIGF 3.4e38f
#define LN2f 0.6931471805599453f
#define SKIP_THR 30.0f

#define DCHUNKS    144               // sum_u ceil((32-u)/4)
#define DENS_BLKS  (16*DCHUNKS)      // 2304
#define CROSS_BLKS 2048              // b(8) * I(32) * ph(8)
#define PTSTOT (NB*NPTS)             // 32768
#define TRIVEC 496

// unpack 8 consecutive xyz points (6 float4) from LDS into register arrays
__device__ __forceinline__ void unpack8(const float4* s4, int base,
                                        float (&X)[8], float (&Y)[8], float (&Z)[8])
{
    float4 A = s4[base+0], B = s4[base+1], C = s4[base+2];
    float4 D = s4[base+3], E = s4[base+4], F = s4[base+5];
    X[0]=A.x; Y[0]=A.y; Z[0]=A.z;  X[1]=A.w; Y[1]=B.x; Z[1]=B.y;
    X[2]=B.z; Y[2]=B.w; Z[2]=C.x;  X[3]=C.y; Y[3]=C.z; Z[3]=C.w;
    X[4]=D.x; Y[4]=D.y; Z[4]=D.z;  X[5]=D.w; Y[5]=E.x; Z[5]=E.y;
    X[6]=E.z; Y[6]=E.w; Z[6]=F.x;  X[7]=F.y; Y[7]=F.z; Z[7]=F.w;
}

// aabb slot layout: [mnx,mny,mnz,pad, mxx,mxy,mxz,pad]
__device__ __forceinline__ float aabbGap2(const float* A, const float* B)
{
    float g, s;
    g = fmaxf(0.f, fmaxf(B[0]-A[4], A[0]-B[4])); s = g*g;
    g = fmaxf(0.f, fmaxf(B[1]-A[5], A[1]-B[5])); s = fmaf(g,g,s);
    g = fmaxf(0.f, fmaxf(B[2]-A[6], A[2]-B[6])); s = fmaf(g,g,s);
    return s;
}

// ==== sort: per (cl,b), counting-sort by 12-bit Morton; per-tile AABBs ======
__global__ __launch_bounds__(1024) void dacl_sort(
    const float* __restrict__ pred, const float* __restrict__ gt,
    float* __restrict__ sortedP,   // [2][8][4096*3]
    float* __restrict__ aabb)      // [(cl*8+b)*32 + tile][8]
{
    __shared__ int h[4096];
    __shared__ int wsum[16];
    const int tid  = threadIdx.x;
    const int lane = tid & 63, wid = tid >> 6;
    const int cb   = blockIdx.x;           // cl*8+b
    const int b    = cb & 7, cl = cb >> 3;
    const float* src = (cl ? gt : pred) + (size_t)b*NPTS*3;
    float* dst = sortedP + (size_t)cb*NPTS*3;

    for (int i = tid; i < 4096; i += 1024) h[i] = 0;
    __syncthreads();

    float px[4], py[4], pz[4]; int code[4];
    #pragma unroll
    for (int k = 0; k < 4; ++k) {
        const int i = k*1024 + tid;
        const float x = src[i*3], y = src[i*3+1], z = src[i*3+2];
        px[k]=x; py[k]=y; pz[k]=z;
        int cx = (int)floorf((x + 4.8f) * (1.0f/0.6f));
        int cy = (int)floorf((y + 4.8f) * (1.0f/0.6f));
        int cz = (int)floorf((z + 4.8f) * (1.0f/0.6f));
        cx = min(max(cx,0),15); cy = min(max(cy,0),15); cz = min(max(cz,0),15);
        int m = 0;
        #pragma unroll
        for (int bit = 0; bit < 4; ++bit)
            m |= (((cx>>bit)&1)<<(3*bit)) | (((cy>>bit)&1)<<(3*bit+1))
               | (((cz>>bit)&1)<<(3*bit+2));
        code[k] = m;
        atomicAdd(&h[m], 1);
    }
    __syncthreads();

    // exclusive scan of 4096 counters (4 per thread)
    const int a0=h[4*tid], a1=h[4*tid+1], a2=h[4*tid+2], a3=h[4*tid+3];
    const int tot = a0+a1+a2+a3;
    int v = tot;
    #pragma unroll
    for (int off = 1; off < 64; off <<= 1) {
        int n = __shfl_up(v, off, 64);
        if (lane >= off) v += n;
    }
    if (lane == 63) wsum[wid] = v;
    __syncthreads();
    if (tid == 0) {
        int run = 0;
        for (int i = 0; i < 16; ++i) { int t = wsum[i]; wsum[i] = run; run += t; }
    }
    __syncthreads();
    const int excl = wsum[wid] + v - tot;
    h[4*tid]   = excl;
    h[4*tid+1] = excl + a0;
    h[4*tid+2] = excl + a0 + a1;
    h[4*tid+3] = excl + a0 + a1 + a2;
    __syncthreads();

    // scatter (within-cell order nondeterministic; sums reassociate ~1e-7)
    #pragma unroll
    for (int k = 0; k < 4; ++k) {
        const int pos = atomicAdd(&h[code[k]], 1);
        dst[pos*3]   = px[k];
        dst[pos*3+1] = py[k];
        dst[pos*3+2] = pz[k];
    }
    __threadfence();
    __syncthreads();

    // per-tile AABB: 32 tiles x 128 pts; 32 lanes per tile, 4 pts each
    {
        const int t = tid >> 5, j = tid & 31;
        float mnx=BIGF,mny=BIGF,mnz=BIGF,mxx=-BIGF,mxy=-BIGF,mxz=-BIGF;
        #pragma unroll
        for (int kk = 0; kk < 4; ++kk) {
            const int i = t*128 + j*4 + kk;
            const float x = dst[i*3], y = dst[i*3+1], z = dst[i*3+2];
            mnx=fminf(mnx,x); mny=fminf(mny,y); mnz=fminf(mnz,z);
            mxx=fmaxf(mxx,x); mxy=fmaxf(mxy,y); mxz=fmaxf(mxz,z);
        }
        #pragma unroll
        for (int off = 1; off < 32; off <<= 1) {
            mnx=fminf(mnx,__shfl_xor(mnx,off,64));
            mny=fminf(mny,__shfl_xor(mny,off,64));
            mnz=fminf(mnz,__shfl_xor(mnz,off,64));
            mxx=fmaxf(mxx,__shfl_xor(mxx,off,64));
            mxy=fmaxf(mxy,__shfl_xor(mxy,off,64));
            mxz=fmaxf(mxz,__shfl_xor(mxz,off,64));
        }
        if (j == 0) {
            float* o = aabb + (size_t)(cb*32 + t)*8;
            o[0]=mnx; o[1]=mny; o[2]=mnz; o[3]=0.f;
            o[4]=mxx; o[5]=mxy; o[6]=mxz; o[7]=0.f;
        }
    }
}

// ==== prep2: partner upper bound UB[b][tile] = max d2(predS[i], gtS[i]) ====
__global__ __launch_bounds__(256) void dacl_prep2(
    const float* __restrict__ sortedP, float* __restrict__ UB)
{
    const int g = blockIdx.x*256 + threadIdx.x;   // [0, 32768)
    const int b = g >> 12, i = g & 4095;
    const float* ps = sortedP + (size_t)b*12288;
    const float* gs = sortedP + (size_t)(8+b)*12288;
    const float dx = ps[i*3]-gs[i*3], dy = ps[i*3+1]-gs[i*3+1],
                dz = ps[i*3+2]-gs[i*3+2];
    float d2 = dx*dx + dy*dy + dz*dz;
    const int lane = threadIdx.x & 63, wid = threadIdx.x >> 6;
    #pragma unroll
    for (int off = 1; off < 64; off <<= 1)
        d2 = fmaxf(d2, __shfl_xor(d2, off, 64));
    __shared__ float wmax[4];
    if (lane == 0) wmax[wid] = d2;
    __syncthreads();
    if (threadIdx.x == 0)   UB[blockIdx.x*2]     = fmaxf(wmax[0], wmax[1]);
    if (threadIdx.x == 128) UB[blockIdx.x*2 + 1] = fmaxf(wmax[2], wmax[3]);
}

// ==== init: minG2Pp <- +BIG, densCol <- 0 (skipped slots must read neutral) =
__global__ __launch_bounds__(256) void dacl_init(
    float* __restrict__ minG2Pp, float* __restrict__ densCol)
{
    const int g = blockIdx.x*256 + threadIdx.x;   // [0, 1048576)
    minG2Pp[g] = BIGF;
    if (g < 16*TRIVEC*TS) densCol[g] = 0.0f;
}

__global__ __launch_bounds__(TPB) void dacl_pairs(
    const float* __restrict__ sortedP, const float* __restrict__ aabb,
    const float* __restrict__ UB,
    const float* __restrict__ bwp, const float* __restrict__ bwg,
    float* __restrict__ minP2Gp,   // [8 ph][PTSTOT]
    float* __restrict__ minG2Pp,   // [32 I][PTSTOT]  (init BIGF)
    float* __restrict__ densCol,   // [(cl*8+b)][TRIVEC][TS]  (init 0)
    float* __restrict__ densRow)   // [8 cj][2 cl][PTSTOT]
{
    __shared__ float4 sCol[384];
    __shared__ float4 sRow[96];
    __shared__ float  sRed[384];

    const int tid  = threadIdx.x;
    const int ty   = tid & 15;
    const int tx   = tid >> 4;
    const int wave = tid >> 6;
    const int lane = tid & 63;
    const int bid  = blockIdx.x;

    if (bid < DENS_BLKS) {
        // ============ density: strip u x chunk of <=4 col tiles ==============
        const int cb = bid / DCHUNKS;       // cl*8 + b
        int rem      = bid - cb * DCHUNKS;
        const int b  = cb & 7;
        const int cl = cb >> 3;

        int u = 0, nc = 8;
        while (rem >= nc) { rem -= nc; ++u; nc = (35 - u) >> 2; }
        const int cj = rem;
        const int js = cj * 4;
        const int steps = 32 - u;
        const int je = (js + 4 < steps) ? js + 4 : steps;
        const int nT = je - js;

        const float* __restrict__ P = sortedP + (size_t)cb*12288;
        float* __restrict__ dCol = densCol + (size_t)cb * (TRIVEC*TS);
        float* __restrict__ dRow = densRow + (size_t)(cj*2 + cl) * PTSTOT + b*NPTS;
        const float bw = cl ? bwg[0] : bwp[0];
        const float s2raw = 0.5f / (bw*bw*LN2f);
        const float sc = sqrtf(s2raw);
        const float* myAB = aabb + (size_t)(cb*32 + u)*8;

        const float4* cb4 = (const float4*)P;

        if (tid < 96) {
            float4 v = cb4[u*96 + tid];
            v.x*=sc; v.y*=sc; v.z*=sc; v.w*=sc;  sRow[tid] = v;
        }
        for (int i = tid; i < nT*96; i += TPB) {
            float4 v = cb4[(u + js)*96 + i];
            v.x*=sc; v.y*=sc; v.z*=sc; v.w*=sc;  sCol[i] = v;
        }
        __syncthreads();

        float rx[8], ry[8], rz[8], nrr[8], racc[8];
        unpack8(sRow, ty*6, rx, ry, rz);
        #pragma unroll
        for (int r = 0; r < 8; ++r) {
            nrr[r]  = -fmaf(rx[r],rx[r], fmaf(ry[r],ry[r], rz[r]*rz[r]));
            racc[r] = 0.0f;
        }

        for (int j = js; j < je; ++j) {
            const int t  = j - js;
            const int TV = u + j;

            if (j > 0) {       // tile-level skip (block-uniform; diag never)
                const float* cAB = aabb + (size_t)(cb*32 + TV)*8;
                if (s2raw * aabbGap2(myAB, cAB) > SKIP_THR) continue;
            }

            float cx[8], cy[8], cz[8];
            unpack8(sCol, t*96 + tx*6, cx, cy, cz);

            if (j == 0) {
                #pragma unroll
                for (int c = 0; c < 8; ++c) {
                    const float ax = 2.0f*cx[c], ay = 2.0f*cy[c], az = 2.0f*cz[c];
                    const float ncc = fmaf(-cx[c],cx[c],
                                      fmaf(-cy[c],cy[c], -cz[c]*cz[c]));
                    #pragma unroll
                    for (int r = 0; r < 8; ++r) {
                        float e = fmaf(ax, rx[r], ncc);
                        e = fmaf(ay, ry[r], e);
                        e = fmaf(az, rz[r], e);
                        racc[r] += __builtin_amdgcn_exp2f(e + nrr[r]);
                    }
                }
            } else {
                float cacc[8];
                #pragma unroll
                for (int c = 0; c < 8; ++c) cacc[c] = 0.0f;
                #pragma unroll
                for (int c = 0; c < 8; ++c) {
                    const float ax = 2.0f*cx[c], ay = 2.0f*cy[c], az = 2.0f*cz[c];
                    const float ncc = fmaf(-cx[c],cx[c],
                                      fmaf(-cy[c],cy[c], -cz[c]*cz[c]));
                    #pragma unroll
                    for (int r = 0; r < 8; ++r) {
                        float e = fmaf(ax, rx[r], ncc);
                        e = fmaf(ay, ry[r], e);
                        e = fmaf(az, rz[r], e);
                        const float k = __builtin_amdgcn_exp2f(e + nrr[r]);
                        racc[r] += k;
                        cacc[c] += k;
                    }
                }
                const int triTV = (TV*(TV-1)) >> 1;
                #pragma unroll
                for (int c = 0; c < 8; ++c) {
                    float v = cacc[c];
                    v += __shfl_xor(v, 1, 64);
                    v += __shfl_xor(v, 2, 64);
                    v += __shfl_xor(v, 4, 64);
                    v += __shfl_xor(v, 8, 64);
                    if (ty == 0)
                        dCol[(triTV + u)*TS + tx*8 + c] = v;
                }
            }
        }
        // row flush: cross-wave gather, one plain store
        {
            float vv[8];
            #pragma unroll
            for (int r = 0; r < 8; ++r) {
                float v = racc[r];
                v += __shfl_xor(v, 16, 64);
                v += __shfl_xor(v, 32, 64);
                vv[r] = v;
            }
            __syncthreads();
            if (wave > 0 && lane < 16) {
                #pragma unroll
                for (int r = 0; r < 8; ++r)
                    sRed[(wave-1)*128 + lane*8 + r] = vv[r];
            }
            __syncthreads();
            if (wave == 0 && lane < 16) {
                #pragma unroll
                for (int r = 0; r < 8; ++r) {
                    const int o = lane*8 + r;
                    dRow[u*TS + o] = (vv[r] + sRed[o])
                                   + (sRed[128+o] + sRed[256+o]);
                }
            }
        }
    } else {
        // ============ cross: pred strip I x 4 gt tiles (one phase) ===========
        const int cb = bid - DENS_BLKS;
        const int b  = cb >> 8;
        const int I  = (cb >> 3) & 31;
        const int ph = cb & 7;

        const float4* pb4 = (const float4*)(sortedP + (size_t)b*12288);
        const float4* gb4 = (const float4*)(sortedP + (size_t)(8+b)*12288);
        const float* pAB  = aabb + (size_t)(b*32 + I)*8;
        const float  UB_I = UB[b*32 + I];

        if (tid < 96) sRow[tid] = pb4[I*96 + tid];
        #pragma unroll
        for (int i = 0; i < 2; ++i) {
            const int o = tid + i*TPB;
            if (o < 384) sCol[o] = gb4[ph*384 + o];
        }
        __syncthreads();

        float rx[8], ry[8], rz[8], rr[8], rmin[8];
        unpack8(sRow, ty*6, rx, ry, rz);
        #pragma unroll
        for (int r = 0; r < 8; ++r) {
            rr[r]   = fmaf(rx[r],rx[r], fmaf(ry[r],ry[r], rz[r]*rz[r]));
            rmin[r] = BIGF;
        }
        float* __restrict__ mg = minG2Pp + (size_t)I*PTSTOT + b*NPTS;

        for (int t = 0; t < 4; ++t) {
            const int J = ph*4 + t;
            const float* gAB = aabb + (size_t)((8+b)*32 + J)*8;
            if (aabbGap2(pAB, gAB) > fmaxf(UB_I, UB[b*32 + J])) continue;

            float cx[8], cy[8], cz[8], cmin[8];
            unpack8(sCol, t*96 + tx*6, cx, cy, cz);
            #pragma unroll
            for (int c = 0; c < 8; ++c) cmin[c] = BIGF;
            #pragma unroll
            for (int c2 = 0; c2 < 4; ++c2) {
                const int c0 = 2*c2, c1 = c0 + 1;
                const float ax0 = -2.0f*cx[c0], ay0 = -2.0f*cy[c0], az0 = -2.0f*cz[c0];
                const float cc0 = fmaf(cx[c0],cx[c0], fmaf(cy[c0],cy[c0], cz[c0]*cz[c0]));
                const float ax1 = -2.0f*cx[c1], ay1 = -2.0f*cy[c1], az1 = -2.0f*cz[c1];
                const float cc1 = fmaf(cx[c1],cx[c1], fmaf(cy[c1],cy[c1], cz[c1]*cz[c1]));
                #pragma unroll
                for (int r2 = 0; r2 < 4; ++r2) {
                    const int r0 = 2*r2, r1 = r0 + 1;
                    float t00 = fmaf(ax0, rx[r0], cc0);
                    t00 = fmaf(ay0, ry[r0], t00); t00 = fmaf(az0, rz[r0], t00);
                    float t01 = fmaf(ax1, rx[r0], cc1);
                    t01 = fmaf(ay1, ry[r0], t01); t01 = fmaf(az1, rz[r0], t01);
                    float t10 = fmaf(ax0, rx[r1], cc0);
                    t10 = fmaf(ay0, ry[r1], t10); t10 = fmaf(az0, rz[r1], t10);
                    float t11 = fmaf(ax1, rx[r1], cc1);
                    t11 = fmaf(ay1, ry[r1], t11); t11 = fmaf(az1, rz[r1], t11);
                    rmin[r0] = fminf(rmin[r0], fminf(t00, t01));
                    rmin[r1] = fminf(rmin[r1], fminf(t10, t11));
                    const float d00 = t00 + rr[r0], d01 = t01 + rr[r0];
                    const float d10 = t10 + rr[r1], d11 = t11 + rr[r1];
                    cmin[c0] = fminf(cmin[c0], fminf(d00, d10));
                    cmin[c1] = fminf(cmin[c1], fminf(d01, d11));
                }
            }
            #pragma unroll
            for (int c = 0; c < 8; ++c) {
                float v = cmin[c];
                v = fminf(v, __shfl_xor(v, 1, 64));
                v = fminf(v, __shfl_xor(v, 2, 64));
                v = fminf(v, __shfl_xor(v, 4, 64));
                v = fminf(v, __shfl_xor(v, 8, 64));
                if (ty == 0)
                    mg[J*TS + tx*8 + c] = v;
            }
        }
        // row-min: cross-wave gather, one plain store per phase
        float vv[8];
        #pragma unroll
        for (int r = 0; r < 8; ++r) {
            float v = rmin[r] + rr[r];
            v = fminf(v, __shfl_xor(v, 16, 64));
            v = fminf(v, __shfl_xor(v, 32, 64));
            vv[r] = v;
        }
        __syncthreads();
        if (wave > 0 && lane < 16) {
            #pragma unroll
            for (int r = 0; r < 8; ++r) sRed[(wave-1)*128 + lane*8 + r] = vv[r];
        }
        __syncthreads();
        if (wave == 0 && lane < 16) {
            #pragma unroll
            for (int r = 0; r < 8; ++r) {
                const int o = lane*8 + r;
                minP2Gp[(size_t)ph*PTSTOT + b*NPTS + I*TS + o] =
                    fminf(fminf(vv[r], sRed[o]),
                          fminf(sRed[128+o], sRed[256+o]));
            }
        }
    }
}

__global__ __launch_bounds__(256) void dacl_combine(
    const float* __restrict__ minP2Gp, const float* __restrict__ minG2Pp,
    const float* __restrict__ densCol, const float* __restrict__ densRow,
    float* __restrict__ bsum)
{
    const int g   = blockIdx.x * 256 + threadIdx.x;  // [0, 65536)
    const int dir = g >> 15;
    const int idx = g & 32767;
    const int b   = idx >> 12;
    const int pt  = idx & 4095;
    const int T   = pt >> 7;
    const int co  = pt & 127;
    const int cl  = dir;

    float m = BIGF;
    if (dir == 0) {
        #pragma unroll
        for (int s = 0; s < 8; ++s) m = fminf(m, minP2Gp[(size_t)s*PTSTOT + idx]);
    } else {
        #pragma unroll
        for (int s = 0; s < 32; ++s) m = fminf(m, minG2Pp[(size_t)s*PTSTOT + idx]);
    }
    m = fmaxf(m, 0.0f);

    float dn = 0.0f;
    const float* dC = densCol + (size_t)(cl*NB + b)*(TRIVEC*TS)
                      + ((T*(T-1)) >> 1)*TS + co;
    for (int RT = 0; RT < T; ++RT) dn += dC[RT*TS];
    const int ncj = (35 - T) >> 2;
    #pragma unroll
    for (int cj = 0; cj < 8; ++cj) {
        if (cj < ncj) dn += densRow[(size_t)(cj*2 + cl)*PTSTOT + idx];
    }

    float val = m / (dn * (1.0f/4095.0f) + 1e-6f) * (1.0f/32768.0f);

    #pragma unroll
    for (int off = 32; off; off >>= 1) val += __shfl_down(val, off);
    __shared__ float sm[4];
    const int lane = threadIdx.x & 63, wid = threadIdx.x >> 6;
    if (lane == 0) sm[wid] = val;
    __syncthreads();
    if (threadIdx.x == 0) bsum[blockIdx.x] = (sm[0] + sm[1]) + (sm[2] + sm[3]);
}

__global__ __launch_bounds__(256) void dacl_final(
    const float* __restrict__ bsum, float* __restrict__ out)
{
    float v = bsum[threadIdx.x];
    #pragma unroll
    for (int off = 32; off; off >>= 1) v += __shfl_down(v, off);
    __shared__ float sm[4];
    const int lane = threadIdx.x & 63, wid = threadIdx.x >> 6;
    if (lane == 0) sm[wid] = v;
    __syncthreads();
    if (threadIdx.x == 0) out[0] = (sm[0] + sm[1]) + (sm[2] + sm[3]);
}

extern "C" void kernel_launch(void* const* d_in, const int* in_sizes, int n_in,
                              void* d_out, int out_size, void* d_ws, size_t ws_size,
                              hipStream_t stream)
{
    const float* pred = (const float*)d_in[0];
    const float* gt   = (const float*)d_in[1];
    const float* bwp  = (const float*)d_in[2];
    const float* bwg  = (const float*)d_in[3];

    float* sortedP  = (float*)d_ws;                     // [16][12288]  786 KB
    float* aabb     = sortedP + (size_t)16*12288;       // [512][8]     16 KB
    float* UBarr    = aabb + 512*8;                     // [256]
    float* minP2Gp  = UBarr + 256;                      // [8][32768]   1 MB
    float* minG2Pp  = minP2Gp + (size_t)8*PTSTOT;       // [32][32768]  4 MB
    float* densCol  = minG2Pp + (size_t)32*PTSTOT;      // [16][496][128] 3.9 MB
    float* densRow  = densCol + (size_t)16*TRIVEC*TS;   // [16][32768]  2 MB
    float* bsum     = densRow + (size_t)16*PTSTOT;      // [256]

    dacl_sort<<<16, 1024, 0, stream>>>(pred, gt, sortedP, aabb);
    dacl_prep2<<<128, 256, 0, stream>>>(sortedP, UBarr);
    dacl_init<<<4096, 256, 0, stream>>>(minG2Pp, densCol);
    dacl_pairs<<<DENS_BLKS + CROSS_BLKS, TPB, 0, stream>>>(
        sortedP, aabb, UBarr, bwp, bwg, minP2Gp, minG2Pp, densCol, densRow);
    dacl_combine<<<256, 256, 0, stream>>>(minP2Gp, minG2Pp, densCol, densRow, bsum);
    dacl_final<<<1, 256, 0, stream>>>(bsum, (float*)d_out);
}